// Round 4
// baseline (430.727 us; speedup 1.0000x reference)
//
#include <hip/hip_runtime.h>

#define NC 24  // N*C = 8*3

typedef float f32x4 __attribute__((ext_vector_type(4)));

// ---------- scalar pyrDown point: 5x5 binomial, reflect-101 ----------
__device__ __forceinline__ float pyr_point(const float* ip, int Hi, int Wi, int oy, int ox)
{
    const float k1[5] = {0.0625f, 0.25f, 0.375f, 0.25f, 0.0625f};
    float acc = 0.f;
#pragma unroll
    for (int i = 0; i < 5; ++i) {
        int y = 2 * oy - 2 + i;
        y = (y < 0) ? -y : y;
        y = (y >= Hi) ? (2 * Hi - 2 - y) : y;
        const float* rp = ip + (size_t)y * Wi;
        float r = 0.f;
#pragma unroll
        for (int j = 0; j < 5; ++j) {
            int xx = 2 * ox - 2 + j;
            xx = (xx < 0) ? -xx : xx;
            xx = (xx >= Wi) ? (2 * Wi - 2 - xx) : xx;
            r = fmaf(k1[j], rp[xx], r);
        }
        acc = fmaf(k1[i], r, acc);
    }
    return acc;
}

// ---------- Gaussian blur point, reflect-101 ----------
template <int K>
__device__ __forceinline__ float blur_point(const float* ip, int H, int W, int oy, int ox,
                                            const float* w)
{
    const int R = K / 2;
    float acc = 0.f;
#pragma unroll
    for (int i = 0; i < K; ++i) {
        int y = oy - R + i;
        y = (y < 0) ? -y : y;
        y = (y >= H) ? (2 * H - 2 - y) : y;
        const float* rp = ip + (size_t)y * W;
        float r = 0.f;
#pragma unroll
        for (int j = 0; j < K; ++j) {
            int xx = ox - R + j;
            xx = (xx < 0) ? -xx : xx;
            xx = (xx >= W) ? (2 * W - 2 - xx) : xx;
            r = fmaf(w[j], rp[xx], r);
        }
        acc = fmaf(w[i], r, acc);
    }
    return acc;
}

// ---------- fused double pyrDown: in (Hi,Wi) -> out (Ho,Wo) = (Hi/4, Wi/4) ----------
// Per block: 64x16 output tile, 4-stage separable pipeline entirely in LDS:
//   A: vertical 5-tap @ input res for 35 mid-level rows  (coalesced global reads)
//   B: horizontal 5-tap -> mid-level tile [35][132]
//   C: vertical 5-tap @ mid res -> [16][132]  (mid-level reflect on row index)
//   D: horizontal 5-tap -> out [16][64]       (mid-level reflect on col index)
// Skips materializing the mid level in global memory entirely.
__global__ void __launch_bounds__(256) dpyrdown_kernel(
    const float* __restrict__ in, float* __restrict__ out,
    int Hi, int Wi, int Hm, int Wm, int Ho, int Wo, float scale, float offs)
{
    __shared__ float vsA[35 * 268];   // 37520 B
    __shared__ float l1t[35 * 132];   // 18480 B
    __shared__ float vsC[16 * 132];   //  8448 B
    const int tid = threadIdx.x;
    const int OX = blockIdx.x * 64;
    const int OY = blockIdx.y * 16;
    const int nc = blockIdx.z;
    const float k1[5] = {0.0625f, 0.25f, 0.375f, 0.25f, 0.0625f};
    const float* ip = in + (size_t)nc * Hi * Wi;
    const int baseX = 4 * OX - 6;     // nominal input col of vsA[.][0]
    const int baseY1 = 2 * OY - 2;    // nominal mid-level row of vsA[0][.]

    // ---- A: vertical conv at input resolution ----
    for (int idx = tid; idx < 35 * 268; idx += 256) {
        int r = idx / 268, c = idx - r * 268;
        int y1 = baseY1 + r;          // nominal mid row (garbage rows never read)
        int xi = baseX + c;           // input-level reflect on col
        xi = (xi < 0) ? -xi : xi;
        xi = (xi >= Wi) ? (2 * Wi - 2 - xi) : xi;
        xi = min(max(xi, 0), Wi - 1);
        float acc = 0.f;
#pragma unroll
        for (int i = 0; i < 5; ++i) {
            int y = 2 * y1 - 2 + i;   // input-level reflect on row
            y = (y < 0) ? -y : y;
            y = (y >= Hi) ? (2 * Hi - 2 - y) : y;
            y = min(max(y, 0), Hi - 1);
            acc = fmaf(k1[i], ip[(size_t)y * Wi + xi], acc);
        }
        vsA[idx] = acc;
    }
    __syncthreads();

    // ---- B: horizontal conv -> mid-level tile ----
    for (int idx = tid; idx < 35 * 132; idx += 256) {
        int r = idx / 132, lc = idx - r * 132;
        const float* vp = &vsA[r * 268 + 2 * lc];
        float acc = 0.f;
#pragma unroll
        for (int j = 0; j < 5; ++j) acc = fmaf(k1[j], vp[j], acc);
        l1t[idx] = acc;
    }
    __syncthreads();

    // ---- C: vertical conv at mid resolution (mid-level reflect on rows) ----
    for (int idx = tid; idx < 16 * 132; idx += 256) {
        int rr = idx / 132, lc = idx - rr * 132;
        int y1n0 = baseY1 + 2 * rr;   // = 2*(OY+rr) - 2
        float acc = 0.f;
#pragma unroll
        for (int i = 0; i < 5; ++i) {
            int y1 = y1n0 + i;
            y1 = (y1 < 0) ? -y1 : y1;
            y1 = (y1 >= Hm) ? (2 * Hm - 2 - y1) : y1;
            int ly = min(max(y1 - baseY1, 0), 34);
            acc = fmaf(k1[i], l1t[ly * 132 + lc], acc);
        }
        vsC[idx] = acc;
    }
    __syncthreads();

    // ---- D: horizontal conv -> out (mid-level reflect on cols) ----
    for (int o = tid; o < 1024; o += 256) {
        int r = o >> 6, c = o & 63;
        int ox = OX + c, oy = OY + r;
        if (ox >= Wo || oy >= Ho) continue;
        float acc = 0.f;
#pragma unroll
        for (int j = 0; j < 5; ++j) {
            int c1 = 2 * ox - 2 + j;
            c1 = (c1 < 0) ? -c1 : c1;
            c1 = (c1 >= Wm) ? (2 * Wm - 2 - c1) : c1;
            int lc = min(max(c1 - (2 * OX - 2), 0), 131);
            acc = fmaf(k1[j], vsC[r * 132 + lc], acc);
        }
        out[((size_t)nc * Ho + oy) * Wo + ox] = fmaf(acc, scale, offs);
    }
}

// ---------- base_kernel: 80 -> {40,20,10,5} + blurs, all in LDS, 1 block/nc ----------
__global__ void __launch_bounds__(512) base_kernel(
    const float* __restrict__ L4g, float* __restrict__ b30g,
    float* __restrict__ b150g, float* __restrict__ b300g)
{
    __shared__ float sL4[80 * 80];
    __shared__ float sL5[40 * 40];
    __shared__ float sL6[20 * 20];
    __shared__ float sL7[10 * 10];
    __shared__ float sL8[5 * 5];
    const int nc = blockIdx.x;
    const int tid = threadIdx.x;

    float w7[7], w9[9];
    {
        float s = 1.4f, s2 = 2.f * s * s, sum = 0.f;
#pragma unroll
        for (int i = 0; i < 7; ++i) { float d = (float)i - 3.f; w7[i] = expf(-(d * d) / s2); sum += w7[i]; }
#pragma unroll
        for (int i = 0; i < 7; ++i) w7[i] /= sum;
        s = 1.7f; s2 = 2.f * s * s; sum = 0.f;
#pragma unroll
        for (int i = 0; i < 9; ++i) { float d = (float)i - 4.f; w9[i] = expf(-(d * d) / s2); sum += w9[i]; }
#pragma unroll
        for (int i = 0; i < 9; ++i) w9[i] /= sum;
    }

    const float* src = L4g + (size_t)nc * 6400;
    for (int i = tid; i < 1600; i += 512)
        *(f32x4*)&sL4[4 * i] = *(const f32x4*)&src[4 * i];
    __syncthreads();
    for (int i = tid; i < 1600; i += 512) {
        int oy = i / 40, ox = i - oy * 40;
        sL5[i] = pyr_point(sL4, 80, 80, oy, ox);
    }
    __syncthreads();
    for (int i = tid; i < 400; i += 512) {
        int oy = i / 20, ox = i - oy * 20;
        sL6[i] = pyr_point(sL5, 40, 40, oy, ox);
    }
    __syncthreads();
    for (int i = tid; i < 100; i += 512) {
        int oy = i / 10, ox = i - oy * 10;
        sL7[i] = pyr_point(sL6, 20, 20, oy, ox);
    }
    __syncthreads();
    for (int i = tid; i < 25; i += 512) {
        int oy = i / 5, ox = i - oy * 5;
        sL8[i] = pyr_point(sL7, 10, 10, oy, ox);
    }
    __syncthreads();
    for (int i = tid; i < 1600; i += 512) {
        int oy = i / 40, ox = i - oy * 40;
        b30g[(size_t)nc * 1600 + i] = blur_point<7>(sL5, 40, 40, oy, ox, w7);
    }
    for (int i = tid; i < 100; i += 512) {
        int oy = i / 10, ox = i - oy * 10;
        b150g[(size_t)nc * 100 + i] = blur_point<9>(sL7, 10, 10, oy, ox, w9);
    }
    for (int i = tid; i < 25; i += 512) {
        int oy = i / 5, ox = i - oy * 5;
        b300g[(size_t)nc * 25 + i] = blur_point<9>(sL8, 5, 5, oy, ox, w9);
    }
}

// ======================= mega_final (unchanged from round 2) =======================
#define CH 1721
#define O30_3 0
#define O30_2 36
#define O30_1 100
#define O30_0 244
#define O150_5 568
#define O150_4 593
#define O150_3 618
#define O150_2 654
#define O150_1 718
#define O150_0 862
#define O300_6 1186
#define O300_5 1211
#define O300_4 1236
#define O300_3 1261
#define O300_2 1297
#define O300_1 1333
#define O300_0 1397

template <int NPL, int ND, int NS, int LSD>
__device__ __forceinline__ void up_level(float* __restrict__ S,
                                         const int (&srcO)[NPL], const int (&dstO)[NPL],
                                         int ayD, int axD, int ayS, int axS)
{
    const int SSRC = LSD / 2;
    const int NPTS = ND * ND;
    for (int pt = threadIdx.x; pt < NPTS; pt += 256) {
        int ry = pt / ND, rx = pt - ry * ND;
        int gy = min(max(ayD + ry, 0), LSD - 1);
        int gx = min(max(axD + rx, 0), LSD - 1);
        int my = gy >> 1, py = gy & 1;
        int mx = gx >> 1, px = gx & 1;
        int yA = py ? my : max(my - 1, 0);
        int yB = py ? min(my + 1, SSRC - 1) : my;
        float wyA = py ? 0.75f : 0.25f;
        float wyB = 1.0f - wyA;
        int xA = px ? mx : max(mx - 1, 0);
        int xB = px ? min(mx + 1, SSRC - 1) : mx;
        float wxA = px ? 0.75f : 0.25f;
        float wxB = 1.0f - wxA;
        int la = (yA - ayS) * NS + (xA - axS);
        int laB = la + (xB - xA);
        int lb = (yB - ayS) * NS + (xA - axS);
        int lbB = lb + (xB - xA);
#pragma unroll
        for (int p = 0; p < NPL; ++p) {
            const float* sp = S + srcO[p];
            float v = wyA * fmaf(wxA, sp[la], wxB * sp[laB]) +
                      wyB * fmaf(wxA, sp[lb], wxB * sp[lbB]);
            S[dstO[p] + pt] = v;
        }
    }
}

__global__ void __launch_bounds__(256) mega_final(
    const float* __restrict__ x,
    const float* __restrict__ b30g,
    const float* __restrict__ b150g,
    const float* __restrict__ b300g,
    float* __restrict__ out)
{
    const int H = 1280, W = 1280;
    __shared__ float S[3 * CH];

    const int tid = threadIdx.x;
    const int X0 = blockIdx.x * 64, Y0 = blockIdx.y * 64;
    const int n = blockIdx.z;

    int ay[7], ax[7];
    ay[0] = (Y0 >> 2) - 1;
    ax[0] = (X0 >> 2) - 1;
#pragma unroll
    for (int l = 1; l < 7; ++l) {
        ay[l] = (ay[l - 1] >> 1) - 1;
        ax[l] = (ax[l - 1] >> 1) - 1;
    }

    if (tid < 36) {                       // b30 at l3: 6x6
        int ry = tid / 6, rx = tid - ry * 6;
        int gy = min(max(ay[3] + ry, 0), 39);
        int gx = min(max(ax[3] + rx, 0), 39);
#pragma unroll
        for (int c = 0; c < 3; ++c)
            S[c * CH + O30_3 + tid] = b30g[(size_t)(n * 3 + c) * 1600 + gy * 40 + gx];
    } else if (tid >= 64 && tid < 89) {   // b150 at l5: 5x5
        int t = tid - 64;
        int ry = t / 5, rx = t - ry * 5;
        int gy = min(max(ay[5] + ry, 0), 9);
        int gx = min(max(ax[5] + rx, 0), 9);
#pragma unroll
        for (int c = 0; c < 3; ++c)
            S[c * CH + O150_5 + t] = b150g[(size_t)(n * 3 + c) * 100 + gy * 10 + gx];
    } else if (tid >= 128 && tid < 153) { // b300 at l6: 5x5
        int t = tid - 128;
        int ry = t / 5, rx = t - ry * 5;
        int gy = min(max(ay[6] + ry, 0), 4);
        int gx = min(max(ax[6] + rx, 0), 4);
#pragma unroll
        for (int c = 0; c < 3; ++c)
            S[c * CH + O300_6 + t] = b300g[(size_t)(n * 3 + c) * 25 + gy * 5 + gx];
    }
    __syncthreads();

    {
        const int s[3] = {O300_6, O300_6 + CH, O300_6 + 2 * CH};
        const int d[3] = {O300_5, O300_5 + CH, O300_5 + 2 * CH};
        up_level<3, 5, 5, 10>(S, s, d, ay[5], ax[5], ay[6], ax[6]);
    }
    __syncthreads();
    {
        const int s[6] = {O300_5, O300_5 + CH, O300_5 + 2 * CH, O150_5, O150_5 + CH, O150_5 + 2 * CH};
        const int d[6] = {O300_4, O300_4 + CH, O300_4 + 2 * CH, O150_4, O150_4 + CH, O150_4 + 2 * CH};
        up_level<6, 5, 5, 20>(S, s, d, ay[4], ax[4], ay[5], ax[5]);
    }
    __syncthreads();
    {
        const int s[6] = {O300_4, O300_4 + CH, O300_4 + 2 * CH, O150_4, O150_4 + CH, O150_4 + 2 * CH};
        const int d[6] = {O300_3, O300_3 + CH, O300_3 + 2 * CH, O150_3, O150_3 + CH, O150_3 + 2 * CH};
        up_level<6, 6, 5, 40>(S, s, d, ay[3], ax[3], ay[4], ax[4]);
    }
    __syncthreads();
    {
        const int s[9] = {O300_3, O300_3 + CH, O300_3 + 2 * CH, O150_3, O150_3 + CH, O150_3 + 2 * CH,
                          O30_3, O30_3 + CH, O30_3 + 2 * CH};
        const int d[9] = {O300_2, O300_2 + CH, O300_2 + 2 * CH, O150_2, O150_2 + CH, O150_2 + 2 * CH,
                          O30_2, O30_2 + CH, O30_2 + 2 * CH};
        up_level<9, 8, 6, 80>(S, s, d, ay[2], ax[2], ay[3], ax[3]);
    }
    __syncthreads();
    {
        const int s[9] = {O300_2, O300_2 + CH, O300_2 + 2 * CH, O150_2, O150_2 + CH, O150_2 + 2 * CH,
                          O30_2, O30_2 + CH, O30_2 + 2 * CH};
        const int d[9] = {O300_1, O300_1 + CH, O300_1 + 2 * CH, O150_1, O150_1 + CH, O150_1 + 2 * CH,
                          O30_1, O30_1 + CH, O30_1 + 2 * CH};
        up_level<9, 12, 8, 160>(S, s, d, ay[1], ax[1], ay[2], ax[2]);
    }
    __syncthreads();
    {
        const int s[9] = {O300_1, O300_1 + CH, O300_1 + 2 * CH, O150_1, O150_1 + CH, O150_1 + 2 * CH,
                          O30_1, O30_1 + CH, O30_1 + 2 * CH};
        const int d[9] = {O300_0, O300_0 + CH, O300_0 + 2 * CH, O150_0, O150_0 + CH, O150_0 + 2 * CH,
                          O30_0, O30_0 + CH, O30_0 + 2 * CH};
        up_level<9, 18, 12, 320>(S, s, d, ay[0], ax[0], ay[1], ax[1]);
    }
    __syncthreads();

    int tyi = tid >> 4, txi = tid & 15;
    int byi = (Y0 >> 2) + tyi, bxi = (X0 >> 2) + txi;
    int ry[3], rx[3];
    ry[0] = max(byi - 1, 0) - ay[0]; ry[1] = byi - ay[0]; ry[2] = min(byi + 1, 319) - ay[0];
    rx[0] = max(bxi - 1, 0) - ax[0]; rx[1] = bxi - ax[0]; rx[2] = min(bxi + 1, 319) - ax[0];
    const int ol0[3] = {O30_0, O150_0, O300_0};

    f32x4 xi[3][4];
#pragma unroll
    for (int c = 0; c < 3; ++c)
#pragma unroll
        for (int qy = 0; qy < 4; ++qy)
            xi[c][qy] = __builtin_nontemporal_load(
                (const f32x4*)&x[((size_t)(n * 3 + c) * H + 4 * byi + qy) * W + 4 * bxi]);

    float crcp[4][4];
#pragma unroll
    for (int qy = 0; qy < 4; ++qy)
#pragma unroll
        for (int qx = 0; qx < 4; ++qx) {
            float s = (xi[0][qy][qx] + xi[1][qy][qx] + xi[2][qy][qx]) * 255.f + 3.f;
            crcp[qy][qx] = __fdividef(2.f, s + 1e-6f);
        }

#pragma unroll
    for (int c = 0; c < 3; ++c) {
        float prod[4][4];
#pragma unroll
        for (int qy = 0; qy < 4; ++qy)
#pragma unroll
            for (int qx = 0; qx < 4; ++qx) prod[qy][qx] = 1.f;

#pragma unroll
        for (int s = 0; s < 3; ++s) {
            const float* fp = &S[c * CH + ol0[s]];
            float v[3][3];
#pragma unroll
            for (int i = 0; i < 3; ++i)
#pragma unroll
                for (int j = 0; j < 3; ++j) v[i][j] = fp[ry[i] * 18 + rx[j]];
            float cy[4][3];
#pragma unroll
            for (int j = 0; j < 3; ++j) {
                float v0 = v[0][j], v1 = v[1][j], v2 = v[2][j];
                cy[0][j] = fmaf(0.375f, v0, 0.625f * v1);
                cy[1][j] = fmaf(0.1875f, v0, fmaf(0.75f, v1, 0.0625f * v2));
                cy[2][j] = fmaf(0.0625f, v0, fmaf(0.75f, v1, 0.1875f * v2));
                cy[3][j] = fmaf(0.625f, v1, 0.375f * v2);
            }
#pragma unroll
            for (int qy = 0; qy < 4; ++qy) {
                float a0 = cy[qy][0], a1 = cy[qy][1], a2 = cy[qy][2];
                float t0 = fmaf(0.375f, a0, 0.625f * a1);
                float t1 = fmaf(0.1875f, a0, fmaf(0.75f, a1, 0.0625f * a2));
                float t2 = fmaf(0.0625f, a0, fmaf(0.75f, a1, 0.1875f * a2));
                float t3 = fmaf(0.625f, a1, 0.375f * a2);
                prod[qy][0] *= (t0 + 1e-6f);
                prod[qy][1] *= (t1 + 1e-6f);
                prod[qy][2] *= (t2 + 1e-6f);
                prod[qy][3] *= (t3 + 1e-6f);
            }
        }

#pragma unroll
        for (int qy = 0; qy < 4; ++qy) {
            f32x4 o;
#pragma unroll
            for (int qx = 0; qx < 4; ++qx) {
                float img = xi[c][qy][qx] * 255.f + 1.f;
                float a = img + 1e-6f;
                float l2a = __log2f(__fdividef(a * a * a, prod[qy][qx]));
                float carg = fmaf(img, crcp[qy][qx], 1.f);
                float l2c = __log2f(carg);
                float e = fmaf(l2a * l2c, 81.55715246f, 128.f);
                e = fminf(fmaxf(e, 0.f), 255.f);
                o[qx] = e * (1.f / 255.f);
            }
            __builtin_nontemporal_store(
                o, (f32x4*)&out[((size_t)(n * 3 + c) * H + 4 * byi + qy) * W + 4 * bxi]);
        }
    }
}

extern "C" void kernel_launch(void* const* d_in, const int* in_sizes, int n_in,
                              void* d_out, int out_size, void* d_ws, size_t ws_size,
                              hipStream_t stream)
{
    const float* x = (const float*)d_in[0];
    float* out = (float*)d_out;
    float* ws = (float*)d_ws;

    size_t off = 0;
    auto alloc = [&](int d) { float* p = ws + off; off += (size_t)NC * d * d; return p; };
    float* L2 = alloc(320);
    float* L4 = alloc(80);
    float* b30 = alloc(40);
    float* b150 = alloc(10);
    float* b300 = alloc(5);
    (void)ws_size; (void)in_sizes; (void)n_in; (void)out_size;

    dim3 blk(256, 1, 1);

    // 1280 -> 320 (applies x*255+1 via linearity of the kernel, sums to 1)
    dpyrdown_kernel<<<dim3(5, 20, NC), blk, 0, stream>>>(
        x, L2, 1280, 1280, 640, 640, 320, 320, 255.f, 1.f);
    // 320 -> 80
    dpyrdown_kernel<<<dim3(2, 5, NC), blk, 0, stream>>>(
        L2, L4, 320, 320, 160, 160, 80, 80, 1.f, 0.f);
    base_kernel<<<dim3(NC, 1, 1), dim3(512, 1, 1), 0, stream>>>(L4, b30, b150, b300);
    mega_final<<<dim3(20, 20, 8), dim3(256, 1, 1), 0, stream>>>(x, b30, b150, b300, out);
}

// Round 6
// 351.490 us; speedup vs baseline: 1.2254x; 1.2254x over previous
//
#include <hip/hip_runtime.h>

#define NC 24  // N*C = 8*3

typedef float f32x4 __attribute__((ext_vector_type(4)));

// ---------- scalar pyrDown point: 5x5 binomial, reflect-101 ----------
__device__ __forceinline__ float pyr_point(const float* ip, int Hi, int Wi, int oy, int ox)
{
    const float k1[5] = {0.0625f, 0.25f, 0.375f, 0.25f, 0.0625f};
    float acc = 0.f;
#pragma unroll
    for (int i = 0; i < 5; ++i) {
        int y = 2 * oy - 2 + i;
        y = (y < 0) ? -y : y;
        y = (y >= Hi) ? (2 * Hi - 2 - y) : y;
        const float* rp = ip + (size_t)y * Wi;
        float r = 0.f;
#pragma unroll
        for (int j = 0; j < 5; ++j) {
            int xx = 2 * ox - 2 + j;
            xx = (xx < 0) ? -xx : xx;
            xx = (xx >= Wi) ? (2 * Wi - 2 - xx) : xx;
            r = fmaf(k1[j], rp[xx], r);
        }
        acc = fmaf(k1[i], r, acc);
    }
    return acc;
}

// ---------- Gaussian blur point, reflect-101 ----------
template <int K>
__device__ __forceinline__ float blur_point(const float* ip, int H, int W, int oy, int ox,
                                            const float* w)
{
    const int R = K / 2;
    float acc = 0.f;
#pragma unroll
    for (int i = 0; i < K; ++i) {
        int y = oy - R + i;
        y = (y < 0) ? -y : y;
        y = (y >= H) ? (2 * H - 2 - y) : y;
        const float* rp = ip + (size_t)y * W;
        float r = 0.f;
#pragma unroll
        for (int j = 0; j < K; ++j) {
            int xx = ox - R + j;
            xx = (xx < 0) ? -xx : xx;
            xx = (xx >= W) ? (2 * W - 2 - xx) : xx;
            r = fmaf(w[j], rp[xx], r);
        }
        acc = fmaf(w[i], r, acc);
    }
    return acc;
}

// ---------- pyrDown v2: tile-to-LDS once (f32x4), separable conv from LDS ----------
// Per block: 64x16 output tile.
//   stage 0: load input tile [35][136] via aligned f32x4 (y-reflect keeps rows whole;
//            x-edge blocks take a scalar reflect path)
//   stage 1: vertical 5-tap from tile -> vs[16][132]
//   stage 2: horizontal 5-tap (stride-2 LDS read = 2-way alias = free) -> out
// All dims compile-time: addressing is shift/add, no runtime muls.
template <int HI, int WI>
__global__ void __launch_bounds__(256) pyrdown_v2(
    const float* __restrict__ in, float* __restrict__ out, float scale, float offs)
{
    const int HO = HI / 2, WO = WI / 2;
    __shared__ float tile[35][136];  // 19040 B ; tile row t <-> input row 2*OY-2+t (reflected)
    __shared__ float vs[16][132];    //  8448 B ; vs col c <-> input col 2*OX-2+c
    const int tid = threadIdx.x;
    const int OX = blockIdx.x * 64;
    const int OY = blockIdx.y * 16;
    const int nc = blockIdx.z;
    const float k1[5] = {0.0625f, 0.25f, 0.375f, 0.25f, 0.0625f};
    const float* ip = in + (size_t)nc * HI * WI;
    const int gx0 = 2 * OX - 4;      // input col of tile[.][0] (16B-aligned when in range)

    // ---- stage 0: global -> LDS tile ----
    if (gx0 >= 0 && gx0 + 135 < WI) {
        // interior in x: whole rows as aligned f32x4
        for (int v = tid; v < 35 * 34; v += 256) {
            int r = v / 34, q = v - r * 34;
            int y = 2 * OY - 2 + r;               // reflect-101 in y
            y = (y < 0) ? -y : y;
            y = (y >= HI) ? (2 * HI - 2 - y) : y;
            *(f32x4*)&tile[r][4 * q] = *(const f32x4*)&ip[(size_t)y * WI + gx0 + 4 * q];
        }
    } else {
        // x-edge: scalar loads with reflect on both axes
        for (int v = tid; v < 35 * 136; v += 256) {
            int r = v / 136, c = v - r * 136;
            int y = 2 * OY - 2 + r;
            y = (y < 0) ? -y : y;
            y = (y >= HI) ? (2 * HI - 2 - y) : y;
            y = min(max(y, 0), HI - 1);
            int x = gx0 + c;
            x = (x < 0) ? -x : x;
            x = (x >= WI) ? (2 * WI - 2 - x) : x;
            x = min(max(x, 0), WI - 1);
            tile[r][c] = ip[(size_t)y * WI + x];
        }
    }
    __syncthreads();

    // ---- stage 1: vertical 5-tap ----
    for (int v = tid; v < 16 * 132; v += 256) {
        int r = v / 132, c = v - r * 132;         // const divisor -> magic mul
        float acc = k1[0] * tile[2 * r][c + 2];
#pragma unroll
        for (int i = 1; i < 5; ++i) acc = fmaf(k1[i], tile[2 * r + i][c + 2], acc);
        vs[r][c] = acc;
    }
    __syncthreads();

    // ---- stage 2: horizontal 5-tap + store (coalesced) ----
    for (int o = tid; o < 1024; o += 256) {
        int r = o >> 6, c = o & 63;
        int ox = OX + c, oy = OY + r;
        if (ox >= WO || oy >= HO) continue;
        float acc = k1[0] * vs[r][2 * c];
#pragma unroll
        for (int j = 1; j < 5; ++j) acc = fmaf(k1[j], vs[r][2 * c + j], acc);
        out[((size_t)nc * HO + oy) * WO + ox] = fmaf(acc, scale, offs);
    }
}

// ---------- base_kernel: 80 -> {40,20,10,5} + blurs, all in LDS, 1 block/nc ----------
__global__ void __launch_bounds__(512) base_kernel(
    const float* __restrict__ L4g, float* __restrict__ b30g,
    float* __restrict__ b150g, float* __restrict__ b300g)
{
    __shared__ float sL4[80 * 80];
    __shared__ float sL5[40 * 40];
    __shared__ float sL6[20 * 20];
    __shared__ float sL7[10 * 10];
    __shared__ float sL8[5 * 5];
    const int nc = blockIdx.x;
    const int tid = threadIdx.x;

    float w7[7], w9[9];
    {
        float s = 1.4f, s2 = 2.f * s * s, sum = 0.f;
#pragma unroll
        for (int i = 0; i < 7; ++i) { float d = (float)i - 3.f; w7[i] = expf(-(d * d) / s2); sum += w7[i]; }
#pragma unroll
        for (int i = 0; i < 7; ++i) w7[i] /= sum;
        s = 1.7f; s2 = 2.f * s * s; sum = 0.f;
#pragma unroll
        for (int i = 0; i < 9; ++i) { float d = (float)i - 4.f; w9[i] = expf(-(d * d) / s2); sum += w9[i]; }
#pragma unroll
        for (int i = 0; i < 9; ++i) w9[i] /= sum;
    }

    const float* src = L4g + (size_t)nc * 6400;
    for (int i = tid; i < 1600; i += 512)
        *(f32x4*)&sL4[4 * i] = *(const f32x4*)&src[4 * i];
    __syncthreads();
    for (int i = tid; i < 1600; i += 512) {
        int oy = i / 40, ox = i - oy * 40;
        sL5[i] = pyr_point(sL4, 80, 80, oy, ox);
    }
    __syncthreads();
    for (int i = tid; i < 400; i += 512) {
        int oy = i / 20, ox = i - oy * 20;
        sL6[i] = pyr_point(sL5, 40, 40, oy, ox);
    }
    __syncthreads();
    for (int i = tid; i < 100; i += 512) {
        int oy = i / 10, ox = i - oy * 10;
        sL7[i] = pyr_point(sL6, 20, 20, oy, ox);
    }
    __syncthreads();
    for (int i = tid; i < 25; i += 512) {
        int oy = i / 5, ox = i - oy * 5;
        sL8[i] = pyr_point(sL7, 10, 10, oy, ox);
    }
    __syncthreads();
    for (int i = tid; i < 1600; i += 512) {
        int oy = i / 40, ox = i - oy * 40;
        b30g[(size_t)nc * 1600 + i] = blur_point<7>(sL5, 40, 40, oy, ox, w7);
    }
    for (int i = tid; i < 100; i += 512) {
        int oy = i / 10, ox = i - oy * 10;
        b150g[(size_t)nc * 100 + i] = blur_point<9>(sL7, 10, 10, oy, ox, w9);
    }
    for (int i = tid; i < 25; i += 512) {
        int oy = i / 5, ox = i - oy * 5;
        b300g[(size_t)nc * 25 + i] = blur_point<9>(sL8, 5, 5, oy, ox, w9);
    }
}

// ======================= mega_final (unchanged from round 2) =======================
#define CH 1721
#define O30_3 0
#define O30_2 36
#define O30_1 100
#define O30_0 244
#define O150_5 568
#define O150_4 593
#define O150_3 618
#define O150_2 654
#define O150_1 718
#define O150_0 862
#define O300_6 1186
#define O300_5 1211
#define O300_4 1236
#define O300_3 1261
#define O300_2 1297
#define O300_1 1333
#define O300_0 1397

template <int NPL, int ND, int NS, int LSD>
__device__ __forceinline__ void up_level(float* __restrict__ S,
                                         const int (&srcO)[NPL], const int (&dstO)[NPL],
                                         int ayD, int axD, int ayS, int axS)
{
    const int SSRC = LSD / 2;
    const int NPTS = ND * ND;
    for (int pt = threadIdx.x; pt < NPTS; pt += 256) {
        int ry = pt / ND, rx = pt - ry * ND;
        int gy = min(max(ayD + ry, 0), LSD - 1);
        int gx = min(max(axD + rx, 0), LSD - 1);
        int my = gy >> 1, py = gy & 1;
        int mx = gx >> 1, px = gx & 1;
        int yA = py ? my : max(my - 1, 0);
        int yB = py ? min(my + 1, SSRC - 1) : my;
        float wyA = py ? 0.75f : 0.25f;
        float wyB = 1.0f - wyA;
        int xA = px ? mx : max(mx - 1, 0);
        int xB = px ? min(mx + 1, SSRC - 1) : mx;
        float wxA = px ? 0.75f : 0.25f;
        float wxB = 1.0f - wxA;
        int la = (yA - ayS) * NS + (xA - axS);
        int laB = la + (xB - xA);
        int lb = (yB - ayS) * NS + (xA - axS);
        int lbB = lb + (xB - xA);
#pragma unroll
        for (int p = 0; p < NPL; ++p) {
            const float* sp = S + srcO[p];
            float v = wyA * fmaf(wxA, sp[la], wxB * sp[laB]) +
                      wyB * fmaf(wxA, sp[lb], wxB * sp[lbB]);
            S[dstO[p] + pt] = v;
        }
    }
}

__global__ void __launch_bounds__(256) mega_final(
    const float* __restrict__ x,
    const float* __restrict__ b30g,
    const float* __restrict__ b150g,
    const float* __restrict__ b300g,
    float* __restrict__ out)
{
    const int H = 1280, W = 1280;
    __shared__ float S[3 * CH];

    const int tid = threadIdx.x;
    const int X0 = blockIdx.x * 64, Y0 = blockIdx.y * 64;
    const int n = blockIdx.z;

    int ay[7], ax[7];
    ay[0] = (Y0 >> 2) - 1;
    ax[0] = (X0 >> 2) - 1;
#pragma unroll
    for (int l = 1; l < 7; ++l) {
        ay[l] = (ay[l - 1] >> 1) - 1;
        ax[l] = (ax[l - 1] >> 1) - 1;
    }

    if (tid < 36) {                       // b30 at l3: 6x6
        int ry = tid / 6, rx = tid - ry * 6;
        int gy = min(max(ay[3] + ry, 0), 39);
        int gx = min(max(ax[3] + rx, 0), 39);
#pragma unroll
        for (int c = 0; c < 3; ++c)
            S[c * CH + O30_3 + tid] = b30g[(size_t)(n * 3 + c) * 1600 + gy * 40 + gx];
    } else if (tid >= 64 && tid < 89) {   // b150 at l5: 5x5
        int t = tid - 64;
        int ry = t / 5, rx = t - ry * 5;
        int gy = min(max(ay[5] + ry, 0), 9);
        int gx = min(max(ax[5] + rx, 0), 9);
#pragma unroll
        for (int c = 0; c < 3; ++c)
            S[c * CH + O150_5 + t] = b150g[(size_t)(n * 3 + c) * 100 + gy * 10 + gx];
    } else if (tid >= 128 && tid < 153) { // b300 at l6: 5x5
        int t = tid - 128;
        int ry = t / 5, rx = t - ry * 5;
        int gy = min(max(ay[6] + ry, 0), 4);
        int gx = min(max(ax[6] + rx, 0), 4);
#pragma unroll
        for (int c = 0; c < 3; ++c)
            S[c * CH + O300_6 + t] = b300g[(size_t)(n * 3 + c) * 25 + gy * 5 + gx];
    }
    __syncthreads();

    {
        const int s[3] = {O300_6, O300_6 + CH, O300_6 + 2 * CH};
        const int d[3] = {O300_5, O300_5 + CH, O300_5 + 2 * CH};
        up_level<3, 5, 5, 10>(S, s, d, ay[5], ax[5], ay[6], ax[6]);
    }
    __syncthreads();
    {
        const int s[6] = {O300_5, O300_5 + CH, O300_5 + 2 * CH, O150_5, O150_5 + CH, O150_5 + 2 * CH};
        const int d[6] = {O300_4, O300_4 + CH, O300_4 + 2 * CH, O150_4, O150_4 + CH, O150_4 + 2 * CH};
        up_level<6, 5, 5, 20>(S, s, d, ay[4], ax[4], ay[5], ax[5]);
    }
    __syncthreads();
    {
        const int s[6] = {O300_4, O300_4 + CH, O300_4 + 2 * CH, O150_4, O150_4 + CH, O150_4 + 2 * CH};
        const int d[6] = {O300_3, O300_3 + CH, O300_3 + 2 * CH, O150_3, O150_3 + CH, O150_3 + 2 * CH};
        up_level<6, 6, 5, 40>(S, s, d, ay[3], ax[3], ay[4], ax[4]);
    }
    __syncthreads();
    {
        const int s[9] = {O300_3, O300_3 + CH, O300_3 + 2 * CH, O150_3, O150_3 + CH, O150_3 + 2 * CH,
                          O30_3, O30_3 + CH, O30_3 + 2 * CH};
        const int d[9] = {O300_2, O300_2 + CH, O300_2 + 2 * CH, O150_2, O150_2 + CH, O150_2 + 2 * CH,
                          O30_2, O30_2 + CH, O30_2 + 2 * CH};
        up_level<9, 8, 6, 80>(S, s, d, ay[2], ax[2], ay[3], ax[3]);
    }
    __syncthreads();
    {
        const int s[9] = {O300_2, O300_2 + CH, O300_2 + 2 * CH, O150_2, O150_2 + CH, O150_2 + 2 * CH,
                          O30_2, O30_2 + CH, O30_2 + 2 * CH};
        const int d[9] = {O300_1, O300_1 + CH, O300_1 + 2 * CH, O150_1, O150_1 + CH, O150_1 + 2 * CH,
                          O30_1, O30_1 + CH, O30_1 + 2 * CH};
        up_level<9, 12, 8, 160>(S, s, d, ay[1], ax[1], ay[2], ax[2]);
    }
    __syncthreads();
    {
        const int s[9] = {O300_1, O300_1 + CH, O300_1 + 2 * CH, O150_1, O150_1 + CH, O150_1 + 2 * CH,
                          O30_1, O30_1 + CH, O30_1 + 2 * CH};
        const int d[9] = {O300_0, O300_0 + CH, O300_0 + 2 * CH, O150_0, O150_0 + CH, O150_0 + 2 * CH,
                          O30_0, O30_0 + CH, O30_0 + 2 * CH};
        up_level<9, 18, 12, 320>(S, s, d, ay[0], ax[0], ay[1], ax[1]);
    }
    __syncthreads();

    int tyi = tid >> 4, txi = tid & 15;
    int byi = (Y0 >> 2) + tyi, bxi = (X0 >> 2) + txi;
    int ry[3], rx[3];
    ry[0] = max(byi - 1, 0) - ay[0]; ry[1] = byi - ay[0]; ry[2] = min(byi + 1, 319) - ay[0];
    rx[0] = max(bxi - 1, 0) - ax[0]; rx[1] = bxi - ax[0]; rx[2] = min(bxi + 1, 319) - ax[0];
    const int ol0[3] = {O30_0, O150_0, O300_0};

    f32x4 xi[3][4];
#pragma unroll
    for (int c = 0; c < 3; ++c)
#pragma unroll
        for (int qy = 0; qy < 4; ++qy)
            xi[c][qy] = __builtin_nontemporal_load(
                (const f32x4*)&x[((size_t)(n * 3 + c) * H + 4 * byi + qy) * W + 4 * bxi]);

    float crcp[4][4];
#pragma unroll
    for (int qy = 0; qy < 4; ++qy)
#pragma unroll
        for (int qx = 0; qx < 4; ++qx) {
            float s = (xi[0][qy][qx] + xi[1][qy][qx] + xi[2][qy][qx]) * 255.f + 3.f;
            crcp[qy][qx] = __fdividef(2.f, s + 1e-6f);
        }

#pragma unroll
    for (int c = 0; c < 3; ++c) {
        float prod[4][4];
#pragma unroll
        for (int qy = 0; qy < 4; ++qy)
#pragma unroll
            for (int qx = 0; qx < 4; ++qx) prod[qy][qx] = 1.f;

#pragma unroll
        for (int s = 0; s < 3; ++s) {
            const float* fp = &S[c * CH + ol0[s]];
            float v[3][3];
#pragma unroll
            for (int i = 0; i < 3; ++i)
#pragma unroll
                for (int j = 0; j < 3; ++j) v[i][j] = fp[ry[i] * 18 + rx[j]];
            float cy[4][3];
#pragma unroll
            for (int j = 0; j < 3; ++j) {
                float v0 = v[0][j], v1 = v[1][j], v2 = v[2][j];
                cy[0][j] = fmaf(0.375f, v0, 0.625f * v1);
                cy[1][j] = fmaf(0.1875f, v0, fmaf(0.75f, v1, 0.0625f * v2));
                cy[2][j] = fmaf(0.0625f, v0, fmaf(0.75f, v1, 0.1875f * v2));
                cy[3][j] = fmaf(0.625f, v1, 0.375f * v2);
            }
#pragma unroll
            for (int qy = 0; qy < 4; ++qy) {
                float a0 = cy[qy][0], a1 = cy[qy][1], a2 = cy[qy][2];
                float t0 = fmaf(0.375f, a0, 0.625f * a1);
                float t1 = fmaf(0.1875f, a0, fmaf(0.75f, a1, 0.0625f * a2));
                float t2 = fmaf(0.0625f, a0, fmaf(0.75f, a1, 0.1875f * a2));
                float t3 = fmaf(0.625f, a1, 0.375f * a2);
                prod[qy][0] *= (t0 + 1e-6f);
                prod[qy][1] *= (t1 + 1e-6f);
                prod[qy][2] *= (t2 + 1e-6f);
                prod[qy][3] *= (t3 + 1e-6f);
            }
        }

#pragma unroll
        for (int qy = 0; qy < 4; ++qy) {
            f32x4 o;
#pragma unroll
            for (int qx = 0; qx < 4; ++qx) {
                float img = xi[c][qy][qx] * 255.f + 1.f;
                float a = img + 1e-6f;
                float l2a = __log2f(__fdividef(a * a * a, prod[qy][qx]));
                float carg = fmaf(img, crcp[qy][qx], 1.f);
                float l2c = __log2f(carg);
                float e = fmaf(l2a * l2c, 81.55715246f, 128.f);
                e = fminf(fmaxf(e, 0.f), 255.f);
                o[qx] = e * (1.f / 255.f);
            }
            __builtin_nontemporal_store(
                o, (f32x4*)&out[((size_t)(n * 3 + c) * H + 4 * byi + qy) * W + 4 * bxi]);
        }
    }
}

extern "C" void kernel_launch(void* const* d_in, const int* in_sizes, int n_in,
                              void* d_out, int out_size, void* d_ws, size_t ws_size,
                              hipStream_t stream)
{
    const float* x = (const float*)d_in[0];
    float* out = (float*)d_out;
    float* ws = (float*)d_ws;

    size_t off = 0;
    auto alloc = [&](int d) { float* p = ws + off; off += (size_t)NC * d * d; return p; };
    float* L1 = alloc(640);
    float* L2 = alloc(320);
    float* L3 = alloc(160);
    float* L4 = alloc(80);
    float* b30 = alloc(40);
    float* b150 = alloc(10);
    float* b300 = alloc(5);
    (void)ws_size; (void)in_sizes; (void)n_in; (void)out_size;

    dim3 blk(256, 1, 1);

    // 1280 -> 640 (folds x*255+1 via kernel linearity, taps sum to 1)
    pyrdown_v2<1280, 1280><<<dim3(10, 40, NC), blk, 0, stream>>>(x,  L1, 255.f, 1.f);
    pyrdown_v2<640, 640><<<dim3(5, 20, NC), blk, 0, stream>>>(L1, L2, 1.f, 0.f);
    pyrdown_v2<320, 320><<<dim3(3, 10, NC), blk, 0, stream>>>(L2, L3, 1.f, 0.f);
    pyrdown_v2<160, 160><<<dim3(2, 5, NC), blk, 0, stream>>>(L3, L4, 1.f, 0.f);
    base_kernel<<<dim3(NC, 1, 1), dim3(512, 1, 1), 0, stream>>>(L4, b30, b150, b300);
    mega_final<<<dim3(20, 20, 8), dim3(256, 1, 1), 0, stream>>>(x, b30, b150, b300, out);
}